// Round 4
// baseline (1694.977 us; speedup 1.0000x reference)
//
#include <hip/hip_runtime.h>

// Problem constants (match reference)
constexpr int N_OP    = 100000;
constexpr int N_M     = 2000;
constexpr int IN_DIM  = 64;
constexpr int OUT_DIM = 128;
constexpr int E_SEQ_N  = 100000;
constexpr int E_OP2M_N = 2000000;

// S layout: scan over [degOp(100000) | degSeq(100000) | trailing 0]
constexpr int OFF_SEQ2 = 100000;
constexpr int SCAN_N2  = 200001;

// m_scatter config: 8 column groups x 16 cols, 32 edge chunks
constexpr int NCG      = 8;
constexpr int NCHUNK   = 32;
constexpr int MS_EDGES = (E_OP2M_N + NCHUNK - 1) / NCHUNK;  // 62500
constexpr int MPAD     = 17;   // LDS row pad: odd stride -> banks spread for random m

// ---------------- Projection: Y[nrows,128] = X[nrows,64] @ W[64,128] + b ----------------
__global__ __launch_bounds__(256) void proj_kernel(
    const float* __restrict__ X, const float* __restrict__ W,
    const float* __restrict__ b, float* __restrict__ Y, int nrows) {
  __shared__ float Ws[IN_DIM * OUT_DIM];   // 32 KB
  __shared__ float bs[OUT_DIM];
  __shared__ float Xs[16 * IN_DIM];        // 4 KB
  const int t = threadIdx.x;
  for (int i = t; i < IN_DIM * OUT_DIM; i += 256) Ws[i] = W[i];
  if (t < OUT_DIM) bs[t] = b[t];
  const int row0 = blockIdx.x * 16;
  const int nr = min(16, nrows - row0);
  for (int i = t; i < nr * IN_DIM; i += 256) Xs[i] = X[(size_t)row0 * IN_DIM + i];
  __syncthreads();
  const int c = t & 127;
  #pragma unroll
  for (int k = 0; k < 8; ++k) {
    const int o = t + k * 256;
    const int r = o >> 7;
    if (r >= nr) break;
    float acc = bs[c];
    #pragma unroll
    for (int j = 0; j < IN_DIM; ++j)
      acc += Xs[r * IN_DIM + j] * Ws[j * OUT_DIM + c];
    Y[(size_t)(row0 + r) * OUT_DIM + c] = acc;
  }
}

// ---------------- op/seq degree counting (low contention: ~20 per address) ----------------
__global__ __launch_bounds__(256) void degree_kernel(
    const int* __restrict__ Eseq, const int* __restrict__ Eop2m,
    int* __restrict__ degOp, int* __restrict__ degSeq) {
  const int stride = gridDim.x * 256;
  const int i = blockIdx.x * 256 + threadIdx.x;
  for (int e = i; e < E_OP2M_N; e += stride) atomicAdd(&degOp[Eop2m[e]], 1);
  for (int e = i; e < E_SEQ_N; e += stride) atomicAdd(&degSeq[Eseq[E_SEQ_N + e]], 1);
}

// ---------------- Hierarchical exclusive scan over [degOp|degSeq] ----------------
__global__ __launch_bounds__(256) void scanA_kernel(
    const int* __restrict__ in, int* __restrict__ out, int* __restrict__ blockSums, int n) {
  __shared__ int s[256];
  const int base = blockIdx.x * 1024 + threadIdx.x * 4;
  int v[4];
  #pragma unroll
  for (int k = 0; k < 4; ++k) v[k] = (base + k < n) ? in[base + k] : 0;
  const int tsum = v[0] + v[1] + v[2] + v[3];
  s[threadIdx.x] = tsum;
  __syncthreads();
  for (int d = 1; d < 256; d <<= 1) {
    const int x = s[threadIdx.x];
    const int y = (threadIdx.x >= d) ? s[threadIdx.x - d] : 0;
    __syncthreads();
    s[threadIdx.x] = x + y;
    __syncthreads();
  }
  int run = s[threadIdx.x] - tsum;
  if (threadIdx.x == 255) blockSums[blockIdx.x] = s[255];
  #pragma unroll
  for (int k = 0; k < 4; ++k) {
    if (base + k < n) out[base + k] = run;
    run += v[k];
  }
}

__global__ __launch_bounds__(256) void scanB_kernel(int* __restrict__ bs, int nb) {
  __shared__ int s[256];
  const int t = threadIdx.x;
  const int v = (t < nb) ? bs[t] : 0;
  s[t] = v;
  __syncthreads();
  for (int d = 1; d < 256; d <<= 1) {
    const int x = s[t];
    const int y = (t >= d) ? s[t - d] : 0;
    __syncthreads();
    s[t] = x + y;
    __syncthreads();
  }
  if (t < nb) bs[t] = s[t] - v;
}

__global__ __launch_bounds__(256) void scanC_kernel(
    int* __restrict__ out, const int* __restrict__ bs, int n) {
  const int base = blockIdx.x * 1024 + threadIdx.x * 4;
  const int add = bs[blockIdx.x];
  #pragma unroll
  for (int k = 0; k < 4; ++k)
    if (base + k < n) out[base + k] += add;
}

// ---------------- Fill op-major packed edge list + seq CSR ----------------
__global__ __launch_bounds__(256) void fill_kernel(
    const int* __restrict__ Eseq, const int* __restrict__ Eop2m, const int* __restrict__ S,
    int* __restrict__ curOp, int* __restrict__ curSeq,
    unsigned* __restrict__ edgeOM, int* __restrict__ seqL) {
  const int stride = gridDim.x * 256;
  const int i = blockIdx.x * 256 + threadIdx.x;
  for (int e = i; e < E_OP2M_N; e += stride) {
    const int op = Eop2m[e];
    const int m  = Eop2m[E_OP2M_N + e];
    const int pos = S[op] + atomicAdd(&curOp[op], 1);
    edgeOM[pos] = ((unsigned)op << 11) | (unsigned)m;
  }
  for (int e = i; e < E_SEQ_N; e += stride) {
    const int src = Eseq[e];
    const int dst = Eseq[E_SEQ_N + e];
    seqL[(S[OFF_SEQ2 + dst] - E_OP2M_N) + atomicAdd(&curSeq[dst], 1)] = src;
  }
}

// ---------------- machine aggregation: op-major stream, LDS machine accumulators ----------------
// grid = (NCHUNK, NCG); 512 threads; LDS 136 KB acc + 8 KB counts (cg 0 only)
__global__ __launch_bounds__(512) void m_scatter_kernel(
    const unsigned* __restrict__ edgeOM, const float* __restrict__ HopProj,
    float* __restrict__ accM, int* __restrict__ degMi) {
  __shared__ float macc[N_M * MPAD];
  __shared__ int hcnt[N_M];
  const int chunk = blockIdx.x;
  const int cg    = blockIdx.y;
  for (int i = threadIdx.x; i < N_M * MPAD; i += 512) macc[i] = 0.f;
  if (cg == 0)
    for (int i = threadIdx.x; i < N_M; i += 512) hcnt[i] = 0;
  __syncthreads();

  const int e0 = chunk * MS_EDGES;
  const int e1 = min(E_OP2M_N, e0 + MS_EDGES);
  const int quad  = threadIdx.x & 3;        // which float4 of the 16 cols
  const int eslot = threadIdx.x >> 2;       // 0..127
  const int colBase = cg * 16 + quad * 4;
  for (int e = e0 + eslot; e < e1; e += 128) {
    const unsigned pk = edgeOM[e];
    const int m  = (int)(pk & 2047u);
    const int op = (int)(pk >> 11);
    const float4 v = *reinterpret_cast<const float4*>(HopProj + (size_t)op * OUT_DIM + colBase);
    float* d = &macc[m * MPAD + quad * 4];
    atomicAdd(d + 0, v.x);
    atomicAdd(d + 1, v.y);
    atomicAdd(d + 2, v.z);
    atomicAdd(d + 3, v.w);
    if (cg == 0 && quad == 0) atomicAdd(&hcnt[m], 1);
  }
  __syncthreads();

  // flush partial sums (low contention: NCHUNK adds per address)
  for (int i = threadIdx.x; i < N_M * 16; i += 512) {
    const int m = i >> 4, c = i & 15;
    const float v = macc[m * MPAD + c];
    if (v != 0.f) atomicAdd(&accM[m * OUT_DIM + cg * 16 + c], v);
  }
  if (cg == 0)
    for (int i = threadIdx.x; i < N_M; i += 512) {
      const int c = hcnt[i];
      if (c) atomicAdd(&degMi[i], c);
    }
}

// ---------------- machine output: relu(HmProj + accM/deg) ----------------
__global__ __launch_bounds__(256) void m_final_kernel(
    const float* __restrict__ HmProj, const float* __restrict__ accM,
    const int* __restrict__ degMi, float* __restrict__ outM) {
  const int idx = blockIdx.x * 256 + threadIdx.x;
  if (idx >= N_M * OUT_DIM) return;
  const int m = idx >> 7;
  outM[idx] = fmaxf(HmProj[idx] + accM[idx] / (float)max(degMi[m], 1), 0.f);
}

// ---------------- op output: one wave per op node, fully fused ----------------
__global__ __launch_bounds__(256) void op_out_kernel(
    const float* __restrict__ HopProj, const float* __restrict__ HmProj,
    const int* __restrict__ S, const unsigned* __restrict__ edgeOM,
    const int* __restrict__ seqL, float* __restrict__ out) {
  const int wid = (blockIdx.x * 256 + threadIdx.x) >> 6;
  if (wid >= N_OP) return;
  const int lane = threadIdx.x & 63;
  const int i = wid;
  float2 acc = *reinterpret_cast<const float2*>(HopProj + (size_t)i * OUT_DIM + lane * 2);

  // seq aggregation (mean over incoming seq edges)
  const int s0 = S[OFF_SEQ2 + i] - E_OP2M_N;
  const int s1 = S[OFF_SEQ2 + i + 1] - E_OP2M_N;
  float2 a = make_float2(0.f, 0.f);
  for (int e = s0; e < s1; ++e) {
    const int src = seqL[e];
    const float2 v = *reinterpret_cast<const float2*>(HopProj + (size_t)src * OUT_DIM + lane * 2);
    a.x += v.x; a.y += v.y;
  }
  const float wS = 1.0f / (float)max(s1 - s0, 1);
  acc.x += a.x * wS; acc.y += a.y * wS;

  // machine aggregation (mean of HmProj over incident op2m edges)
  const int o0 = S[i];
  const int o1 = S[i + 1];
  float2 b = make_float2(0.f, 0.f);
  int e = o0;
  for (; e + 4 <= o1; e += 4) {
    const int m0 = (int)(edgeOM[e]     & 2047u);
    const int m1 = (int)(edgeOM[e + 1] & 2047u);
    const int m2 = (int)(edgeOM[e + 2] & 2047u);
    const int m3 = (int)(edgeOM[e + 3] & 2047u);
    const float2 v0 = *reinterpret_cast<const float2*>(HmProj + (size_t)m0 * OUT_DIM + lane * 2);
    const float2 v1 = *reinterpret_cast<const float2*>(HmProj + (size_t)m1 * OUT_DIM + lane * 2);
    const float2 v2 = *reinterpret_cast<const float2*>(HmProj + (size_t)m2 * OUT_DIM + lane * 2);
    const float2 v3 = *reinterpret_cast<const float2*>(HmProj + (size_t)m3 * OUT_DIM + lane * 2);
    b.x += (v0.x + v1.x) + (v2.x + v3.x);
    b.y += (v0.y + v1.y) + (v2.y + v3.y);
  }
  for (; e < o1; ++e) {
    const int m0 = (int)(edgeOM[e] & 2047u);
    const float2 v0 = *reinterpret_cast<const float2*>(HmProj + (size_t)m0 * OUT_DIM + lane * 2);
    b.x += v0.x; b.y += v0.y;
  }
  const float wO = 1.0f / (float)max(o1 - o0, 1);
  acc.x = fmaxf(acc.x + b.x * wO, 0.f);
  acc.y = fmaxf(acc.y + b.y * wO, 0.f);
  *reinterpret_cast<float2*>(out + (size_t)i * OUT_DIM + lane * 2) = acc;
}

extern "C" void kernel_launch(void* const* d_in, const int* in_sizes, int n_in,
                              void* d_out, int out_size, void* d_ws, size_t ws_size,
                              hipStream_t stream) {
  const float* H_op   = (const float*)d_in[0];
  const float* H_m    = (const float*)d_in[1];
  const int*   E_seq  = (const int*)d_in[2];
  const int*   E_op2m = (const int*)d_in[3];
  const float* W_op   = (const float*)d_in[4];
  const float* b_op   = (const float*)d_in[5];
  const float* W_m    = (const float*)d_in[6];
  const float* b_m    = (const float*)d_in[7];
  float* out = (float*)d_out;

  // ---- workspace layout (element offsets, 4B each) ----
  float* HopProj = (float*)d_ws;                                // 12,800,000
  float* HmProj  = HopProj + (size_t)N_OP * OUT_DIM;            //    256,000
  // zeroed region (contiguous):
  int*   degOp   = (int*)(HmProj + (size_t)N_M * OUT_DIM);      //    100,000
  int*   degSeq  = degOp + N_OP;                                //    100,000
  int*   curOp   = degSeq + N_OP;                               //    100,000
  int*   curSeq  = curOp + N_OP;                                //    100,000
  int*   degMi   = curSeq + N_OP;                               //      2,048
  float* accM    = (float*)(degMi + 2048);                      //    256,000
  // end zeroed region
  int*   S       = (int*)(accM + (size_t)N_M * OUT_DIM);        //    200,704
  int*   bsums   = S + 200704;                                  //        512
  unsigned* edgeOM = (unsigned*)(bsums + 512);                  //  2,000,000
  int*   seqL    = (int*)(edgeOM + E_OP2M_N);                   //    100,000

  // 1. projections
  proj_kernel<<<(N_OP + 15) / 16, 256, 0, stream>>>(H_op, W_op, b_op, HopProj, N_OP);
  proj_kernel<<<(N_M + 15) / 16, 256, 0, stream>>>(H_m, W_m, b_m, HmProj, N_M);

  // 2. zero deg/cur/degMi/accM (one contiguous memset)
  const size_t zero_bytes = ((size_t)4 * N_OP + 2048 + (size_t)N_M * OUT_DIM) * sizeof(int);
  hipMemsetAsync(degOp, 0, zero_bytes, stream);

  // 3. degrees (op & seq sides only; machine degree comes from m_scatter)
  degree_kernel<<<1024, 256, 0, stream>>>(E_seq, E_op2m, degOp, degSeq);

  // 4. exclusive scan of [degOp|degSeq] -> S
  const int nScanBlocks = (SCAN_N2 + 1023) / 1024;   // 196
  scanA_kernel<<<nScanBlocks, 256, 0, stream>>>(degOp, S, bsums, SCAN_N2);
  scanB_kernel<<<1, 256, 0, stream>>>(bsums, nScanBlocks);
  scanC_kernel<<<nScanBlocks, 256, 0, stream>>>(S, bsums, SCAN_N2);

  // 5. fill packed op-major edge list + seq CSR
  fill_kernel<<<2048, 256, 0, stream>>>(E_seq, E_op2m, S, curOp, curSeq, edgeOM, seqL);

  // 6. machine aggregation (op-major stream, LDS accumulators)
  m_scatter_kernel<<<dim3(NCHUNK, NCG), 512, 0, stream>>>(edgeOM, HopProj, accM, degMi);

  // 7. op output (fused residual+relu)
  {
    const long long threads = (long long)N_OP * 64;
    op_out_kernel<<<(int)((threads + 255) / 256), 256, 0, stream>>>(
        HopProj, HmProj, S, edgeOM, seqL, out);
  }

  // 8. machine output
  m_final_kernel<<<(N_M * OUT_DIM + 255) / 256, 256, 0, stream>>>(
      HmProj, accM, degMi, out + (size_t)N_OP * OUT_DIM);
}

// Round 5
// 559.838 us; speedup vs baseline: 3.0276x; 3.0276x over previous
//
#include <hip/hip_runtime.h>

// Problem constants (match reference)
constexpr int N_OP    = 100000;
constexpr int N_M     = 2000;
constexpr int IN_DIM  = 64;
constexpr int OUT_DIM = 128;
constexpr int E_SEQ_N  = 100000;
constexpr int E_OP2M_N = 2000000;

// Counting-sort partitioning for the machine axis
constexpr int W_BLK     = 512;                       // partitions of the edge list
constexpr int CHUNK     = (E_OP2M_N + W_BLK - 1) / W_BLK;  // 3907
constexpr int SEQ_CHUNK = (E_SEQ_N + W_BLK - 1) / W_BLK;   // 196

// S layout: scan over [degOp(100000) | degSeq(100000) | trailing 0]
constexpr int OFF_SEQ2 = 100000;
constexpr int SCAN_N2  = 200001;

// ---------------- Projection: Y[nrows,128] = X[nrows,64] @ W[64,128] + b ----------------
__global__ __launch_bounds__(256) void proj_kernel(
    const float* __restrict__ X, const float* __restrict__ W,
    const float* __restrict__ b, float* __restrict__ Y, int nrows) {
  __shared__ float Ws[IN_DIM * OUT_DIM];   // 32 KB
  __shared__ float bs[OUT_DIM];
  __shared__ float Xs[16 * IN_DIM];        // 4 KB
  const int t = threadIdx.x;
  for (int i = t; i < IN_DIM * OUT_DIM; i += 256) Ws[i] = W[i];
  if (t < OUT_DIM) bs[t] = b[t];
  const int row0 = blockIdx.x * 16;
  const int nr = min(16, nrows - row0);
  for (int i = t; i < nr * IN_DIM; i += 256) Xs[i] = X[(size_t)row0 * IN_DIM + i];
  __syncthreads();
  const int c = t & 127;
  #pragma unroll
  for (int k = 0; k < 8; ++k) {
    const int o = t + k * 256;
    const int r = o >> 7;
    if (r >= nr) break;
    float acc = bs[c];
    #pragma unroll
    for (int j = 0; j < IN_DIM; ++j)
      acc += Xs[r * IN_DIM + j] * Ws[j * OUT_DIM + c];
    Y[(size_t)(row0 + r) * OUT_DIM + c] = acc;
  }
}

// ---------------- Phase A: per-block m-histogram + op/seq degree atomics ----------------
__global__ __launch_bounds__(256) void histA_kernel(
    const int* __restrict__ Eseq, const int* __restrict__ Eop2m,
    int* __restrict__ H, int* __restrict__ degOp, int* __restrict__ degSeq) {
  __shared__ int h[N_M];   // 8 KB
  for (int i = threadIdx.x; i < N_M; i += 256) h[i] = 0;
  __syncthreads();
  const int w = blockIdx.x;
  const int e0 = w * CHUNK, e1 = min(E_OP2M_N, e0 + CHUNK);
  for (int e = e0 + threadIdx.x; e < e1; e += 256) {
    atomicAdd(&degOp[Eop2m[e]], 1);
    atomicAdd(&h[Eop2m[E_OP2M_N + e]], 1);
  }
  const int s0 = w * SEQ_CHUNK, s1 = min(E_SEQ_N, s0 + SEQ_CHUNK);
  for (int e = s0 + threadIdx.x; e < s1; e += 256)
    atomicAdd(&degSeq[Eseq[E_SEQ_N + e]], 1);
  __syncthreads();
  for (int i = threadIdx.x; i < N_M; i += 256) H[w * N_M + i] = h[i];
}

// ---------------- Phase B: exclusive column scan of H; degM = column sums ----------------
__global__ __launch_bounds__(512) void colscan_kernel(int* __restrict__ H, int* __restrict__ degM) {
  __shared__ int s[W_BLK];
  const int m = blockIdx.x;
  const int t = threadIdx.x;
  const int v = H[t * N_M + m];
  s[t] = v;
  __syncthreads();
  for (int d = 1; d < W_BLK; d <<= 1) {
    const int x = s[t];
    const int y = (t >= d) ? s[t - d] : 0;
    __syncthreads();
    s[t] = x + y;
    __syncthreads();
  }
  H[t * N_M + m] = s[t] - v;           // exclusive offset of block t within machine m
  if (t == W_BLK - 1) degM[m] = s[W_BLK - 1];
}

// ---------------- baseM: exclusive scan of degM (2000 elems, 1 block) ----------------
__global__ __launch_bounds__(256) void scanM_kernel(
    const int* __restrict__ degM, int* __restrict__ baseM) {
  __shared__ int s[256];
  const int t = threadIdx.x;
  int v[8];
  int sum = 0;
  #pragma unroll
  for (int k = 0; k < 8; ++k) {
    const int i = t * 8 + k;
    v[k] = (i < N_M) ? degM[i] : 0;
    sum += v[k];
  }
  s[t] = sum;
  __syncthreads();
  for (int d = 1; d < 256; d <<= 1) {
    const int x = s[t];
    const int y = (t >= d) ? s[t - d] : 0;
    __syncthreads();
    s[t] = x + y;
    __syncthreads();
  }
  int run = s[t] - sum;
  #pragma unroll
  for (int k = 0; k < 8; ++k) {
    const int i = t * 8 + k;
    if (i < N_M) baseM[i] = run;
    run += v[k];
  }
}

// ---------------- Hierarchical exclusive scan over [degOp|degSeq] ----------------
__global__ __launch_bounds__(256) void scanA_kernel(
    const int* __restrict__ in, int* __restrict__ out, int* __restrict__ blockSums, int n) {
  __shared__ int s[256];
  const int base = blockIdx.x * 1024 + threadIdx.x * 4;
  int v[4];
  #pragma unroll
  for (int k = 0; k < 4; ++k) v[k] = (base + k < n) ? in[base + k] : 0;
  const int tsum = v[0] + v[1] + v[2] + v[3];
  s[threadIdx.x] = tsum;
  __syncthreads();
  for (int d = 1; d < 256; d <<= 1) {
    const int x = s[threadIdx.x];
    const int y = (threadIdx.x >= d) ? s[threadIdx.x - d] : 0;
    __syncthreads();
    s[threadIdx.x] = x + y;
    __syncthreads();
  }
  int run = s[threadIdx.x] - tsum;
  if (threadIdx.x == 255) blockSums[blockIdx.x] = s[255];
  #pragma unroll
  for (int k = 0; k < 4; ++k) {
    if (base + k < n) out[base + k] = run;
    run += v[k];
  }
}

__global__ __launch_bounds__(256) void scanB_kernel(int* __restrict__ bs, int nb) {
  __shared__ int s[256];
  const int t = threadIdx.x;
  const int v = (t < nb) ? bs[t] : 0;
  s[t] = v;
  __syncthreads();
  for (int d = 1; d < 256; d <<= 1) {
    const int x = s[t];
    const int y = (t >= d) ? s[t - d] : 0;
    __syncthreads();
    s[t] = x + y;
    __syncthreads();
  }
  if (t < nb) bs[t] = s[t] - v;
}

__global__ __launch_bounds__(256) void scanC_kernel(
    int* __restrict__ out, const int* __restrict__ bs, int n) {
  const int base = blockIdx.x * 1024 + threadIdx.x * 4;
  const int add = bs[blockIdx.x];
  #pragma unroll
  for (int k = 0; k < 4; ++k)
    if (base + k < n) out[base + k] += add;
}

// ---------------- Fill all three adjacency lists ----------------
// mL via counting-sort offsets (LDS cursors only); opL/seqL via low-contention cursors.
__global__ __launch_bounds__(256) void fill_kernel(
    const int* __restrict__ Eseq, const int* __restrict__ Eop2m,
    const int* __restrict__ S, const int* __restrict__ H, const int* __restrict__ baseM,
    int* __restrict__ curOp, int* __restrict__ curSeq,
    int* __restrict__ opL, int* __restrict__ mL, int* __restrict__ seqL) {
  __shared__ int lcur[N_M];   // 8 KB
  for (int i = threadIdx.x; i < N_M; i += 256) lcur[i] = 0;
  __syncthreads();
  const int w = blockIdx.x;
  const int base = w * N_M;
  const int e0 = w * CHUNK, e1 = min(E_OP2M_N, e0 + CHUNK);
  for (int e = e0 + threadIdx.x; e < e1; e += 256) {
    const int op = Eop2m[e];
    const int m  = Eop2m[E_OP2M_N + e];
    opL[S[op] + atomicAdd(&curOp[op], 1)] = m;
    mL[baseM[m] + H[base + m] + atomicAdd(&lcur[m], 1)] = op;
  }
  const int s0 = w * SEQ_CHUNK, s1 = min(E_SEQ_N, s0 + SEQ_CHUNK);
  for (int e = s0 + threadIdx.x; e < s1; e += 256) {
    const int src = Eseq[e];
    const int dst = Eseq[E_SEQ_N + e];
    // seqL segment base: S[OFF_SEQ2+dst] - S[OFF_SEQ2]; S[OFF_SEQ2] == E_OP2M_N by construction
    seqL[(S[OFF_SEQ2 + dst] - E_OP2M_N) + atomicAdd(&curSeq[dst], 1)] = src;
  }
}

// ---------------- op output: one wave per op node, fully fused ----------------
__global__ __launch_bounds__(256) void op_out_kernel(
    const float* __restrict__ HopProj, const float* __restrict__ HmProj,
    const int* __restrict__ S, const int* __restrict__ opL,
    const int* __restrict__ seqL, float* __restrict__ out) {
  const int wid = (blockIdx.x * 256 + threadIdx.x) >> 6;
  if (wid >= N_OP) return;
  const int lane = threadIdx.x & 63;
  const int i = wid;
  float2 acc = *reinterpret_cast<const float2*>(HopProj + (size_t)i * OUT_DIM + lane * 2);

  // seq aggregation (mean over incoming seq edges)
  const int s0 = S[OFF_SEQ2 + i] - E_OP2M_N;
  const int s1 = S[OFF_SEQ2 + i + 1] - E_OP2M_N;
  float2 a = make_float2(0.f, 0.f);
  for (int e = s0; e < s1; ++e) {
    const int src = seqL[e];
    const float2 v = *reinterpret_cast<const float2*>(HopProj + (size_t)src * OUT_DIM + lane * 2);
    a.x += v.x; a.y += v.y;
  }
  const float wS = 1.0f / (float)max(s1 - s0, 1);
  acc.x += a.x * wS; acc.y += a.y * wS;

  // machine aggregation (mean of HmProj over incident op2m edges)
  const int o0 = S[i];
  const int o1 = S[i + 1];
  float2 b = make_float2(0.f, 0.f);
  int e = o0;
  for (; e + 4 <= o1; e += 4) {
    const int m0 = opL[e];
    const int m1 = opL[e + 1];
    const int m2 = opL[e + 2];
    const int m3 = opL[e + 3];
    const float2 v0 = *reinterpret_cast<const float2*>(HmProj + (size_t)m0 * OUT_DIM + lane * 2);
    const float2 v1 = *reinterpret_cast<const float2*>(HmProj + (size_t)m1 * OUT_DIM + lane * 2);
    const float2 v2 = *reinterpret_cast<const float2*>(HmProj + (size_t)m2 * OUT_DIM + lane * 2);
    const float2 v3 = *reinterpret_cast<const float2*>(HmProj + (size_t)m3 * OUT_DIM + lane * 2);
    b.x += (v0.x + v1.x) + (v2.x + v3.x);
    b.y += (v0.y + v1.y) + (v2.y + v3.y);
  }
  for (; e < o1; ++e) {
    const int m0 = opL[e];
    const float2 v0 = *reinterpret_cast<const float2*>(HmProj + (size_t)m0 * OUT_DIM + lane * 2);
    b.x += v0.x; b.y += v0.y;
  }
  const float wO = 1.0f / (float)max(o1 - o0, 1);
  acc.x = fmaxf(acc.x + b.x * wO, 0.f);
  acc.y = fmaxf(acc.y + b.y * wO, 0.f);
  *reinterpret_cast<float2*>(out + (size_t)i * OUT_DIM + lane * 2) = acc;
}

// ---------------- machine output: one block per machine, float4 + 4-deep MLP ----------------
// 512 threads: 16 edge slots x 32 col-quads; LDS reduce; fused mean+residual+relu.
__global__ __launch_bounds__(512) void m_out_kernel(
    const float* __restrict__ HopProj, const float* __restrict__ HmProj,
    const int* __restrict__ mL, const int* __restrict__ baseM, const int* __restrict__ degM,
    float* __restrict__ outM) {
  __shared__ float red[16][129];    // 129 pad: conflict-free column reads in reduce
  const int m = blockIdx.x;
  const int s0 = baseM[m];
  const int deg = degM[m];
  const int c4   = (threadIdx.x & 31) << 2;   // column base 0..124
  const int slot = threadIdx.x >> 5;          // 0..15
  float ax = 0.f, ay = 0.f, az = 0.f, aw = 0.f;
  int e = slot;
  for (; e + 48 < deg; e += 64) {
    const int o0 = mL[s0 + e];
    const int o1 = mL[s0 + e + 16];
    const int o2 = mL[s0 + e + 32];
    const int o3 = mL[s0 + e + 48];
    const float4 v0 = *reinterpret_cast<const float4*>(HopProj + (size_t)o0 * OUT_DIM + c4);
    const float4 v1 = *reinterpret_cast<const float4*>(HopProj + (size_t)o1 * OUT_DIM + c4);
    const float4 v2 = *reinterpret_cast<const float4*>(HopProj + (size_t)o2 * OUT_DIM + c4);
    const float4 v3 = *reinterpret_cast<const float4*>(HopProj + (size_t)o3 * OUT_DIM + c4);
    ax += (v0.x + v1.x) + (v2.x + v3.x);
    ay += (v0.y + v1.y) + (v2.y + v3.y);
    az += (v0.z + v1.z) + (v2.z + v3.z);
    aw += (v0.w + v1.w) + (v2.w + v3.w);
  }
  for (; e < deg; e += 16) {
    const int o = mL[s0 + e];
    const float4 v = *reinterpret_cast<const float4*>(HopProj + (size_t)o * OUT_DIM + c4);
    ax += v.x; ay += v.y; az += v.z; aw += v.w;
  }
  red[slot][c4 + 0] = ax;
  red[slot][c4 + 1] = ay;
  red[slot][c4 + 2] = az;
  red[slot][c4 + 3] = aw;
  __syncthreads();
  if (threadIdx.x < 128) {
    const int col = threadIdx.x;
    float s = 0.f;
    #pragma unroll
    for (int k = 0; k < 16; ++k) s += red[k][col];
    const float v = HmProj[m * OUT_DIM + col] + s / (float)max(deg, 1);
    outM[m * OUT_DIM + col] = fmaxf(v, 0.f);
  }
}

extern "C" void kernel_launch(void* const* d_in, const int* in_sizes, int n_in,
                              void* d_out, int out_size, void* d_ws, size_t ws_size,
                              hipStream_t stream) {
  const float* H_op   = (const float*)d_in[0];
  const float* H_m    = (const float*)d_in[1];
  const int*   E_seq  = (const int*)d_in[2];
  const int*   E_op2m = (const int*)d_in[3];
  const float* W_op   = (const float*)d_in[4];
  const float* b_op   = (const float*)d_in[5];
  const float* W_m    = (const float*)d_in[6];
  const float* b_m    = (const float*)d_in[7];
  float* out = (float*)d_out;

  // ---- workspace layout (element offsets, 4B each) ----
  float* HopProj = (float*)d_ws;                                // 12,800,000
  float* HmProj  = HopProj + (size_t)N_OP * OUT_DIM;            //    256,000
  int*   degOp   = (int*)(HmProj + (size_t)N_M * OUT_DIM);      //    100,000 (zeroed)
  int*   degSeq  = degOp + N_OP;                                //    100,000 (zeroed)
  int*   curOp   = degSeq + N_OP;                               //    100,000 (zeroed)
  int*   curSeq  = curOp + N_OP;                                //    100,000 (zeroed)
  int*   degM    = curSeq + N_OP;                               //      2,048
  int*   baseM   = degM + 2048;                                 //      2,048
  int*   S       = baseM + 2048;                                //    200,704
  int*   bsums   = S + 200704;                                  //        512
  int*   Hh      = bsums + 512;                                 //  1,024,000 (W_BLK * N_M)
  int*   opL     = Hh + (size_t)W_BLK * N_M;                    //  2,000,000
  int*   mL      = opL + E_OP2M_N;                              //  2,000,000
  int*   seqL    = mL + E_OP2M_N;                               //    100,000

  // 1. projections
  proj_kernel<<<(N_OP + 15) / 16, 256, 0, stream>>>(H_op, W_op, b_op, HopProj, N_OP);
  proj_kernel<<<(N_M + 15) / 16, 256, 0, stream>>>(H_m, W_m, b_m, HmProj, N_M);

  // 2. zero degOp/degSeq/curOp/curSeq (contiguous)
  hipMemsetAsync(degOp, 0, (size_t)4 * N_OP * sizeof(int), stream);

  // 3. machine histograms + op/seq degrees
  histA_kernel<<<W_BLK, 256, 0, stream>>>(E_seq, E_op2m, Hh, degOp, degSeq);

  // 4. column scan of H -> per-block offsets + degM; then baseM
  colscan_kernel<<<N_M, W_BLK, 0, stream>>>(Hh, degM);
  scanM_kernel<<<1, 256, 0, stream>>>(degM, baseM);

  // 5. exclusive scan of [degOp|degSeq] -> S
  const int nScanBlocks = (SCAN_N2 + 1023) / 1024;   // 196
  scanA_kernel<<<nScanBlocks, 256, 0, stream>>>(degOp, S, bsums, SCAN_N2);
  scanB_kernel<<<1, 256, 0, stream>>>(bsums, nScanBlocks);
  scanC_kernel<<<nScanBlocks, 256, 0, stream>>>(S, bsums, SCAN_N2);

  // 6. fill adjacency lists
  fill_kernel<<<W_BLK, 256, 0, stream>>>(E_seq, E_op2m, S, Hh, baseM,
                                         curOp, curSeq, opL, mL, seqL);

  // 7. outputs
  {
    const long long threads = (long long)N_OP * 64;
    op_out_kernel<<<(int)((threads + 255) / 256), 256, 0, stream>>>(
        HopProj, HmProj, S, opL, seqL, out);
  }
  m_out_kernel<<<N_M, 512, 0, stream>>>(HopProj, HmProj, mL, baseM, degM,
                                        out + (size_t)N_OP * OUT_DIM);
}

// Round 6
// 469.378 us; speedup vs baseline: 3.6111x; 1.1927x over previous
//
#include <hip/hip_runtime.h>

// Problem constants (match reference)
constexpr int N_OP    = 100000;
constexpr int N_M     = 2000;
constexpr int IN_DIM  = 64;
constexpr int OUT_DIM = 128;
constexpr int E_SEQ_N  = 100000;
constexpr int E_OP2M_N = 2000000;

// Counting-sort partitioning for the machine axis
constexpr int W_BLK     = 512;                       // partitions of the edge list
constexpr int CHUNK     = (E_OP2M_N + W_BLK - 1) / W_BLK;  // 3907
constexpr int SEQ_CHUNK = (E_SEQ_N + W_BLK - 1) / W_BLK;   // 196

// S layout: scan over [degOp(100000) | degSeq(100000) | trailing 0]
constexpr int OFF_SEQ2 = 100000;
constexpr int SCAN_N2  = 200001;

__device__ __forceinline__ float bf2f(unsigned short h) {
  return __uint_as_float((unsigned)h << 16);
}

// ---------------- Projection: Y[nrows,128] = X[nrows,64] @ W[64,128] + b ----------------
// Also emits a bf16 (RNE) copy Yh for the bandwidth-bound machine gather.
__global__ __launch_bounds__(256) void proj_kernel(
    const float* __restrict__ X, const float* __restrict__ W,
    const float* __restrict__ b, float* __restrict__ Y,
    unsigned short* __restrict__ Yh, int nrows) {
  __shared__ float Ws[IN_DIM * OUT_DIM];   // 32 KB
  __shared__ float bs[OUT_DIM];
  __shared__ float Xs[16 * IN_DIM];        // 4 KB
  const int t = threadIdx.x;
  for (int i = t; i < IN_DIM * OUT_DIM; i += 256) Ws[i] = W[i];
  if (t < OUT_DIM) bs[t] = b[t];
  const int row0 = blockIdx.x * 16;
  const int nr = min(16, nrows - row0);
  for (int i = t; i < nr * IN_DIM; i += 256) Xs[i] = X[(size_t)row0 * IN_DIM + i];
  __syncthreads();
  const int c = t & 127;
  #pragma unroll
  for (int k = 0; k < 8; ++k) {
    const int o = t + k * 256;
    const int r = o >> 7;
    if (r >= nr) break;
    float acc = bs[c];
    #pragma unroll
    for (int j = 0; j < IN_DIM; ++j)
      acc += Xs[r * IN_DIM + j] * Ws[j * OUT_DIM + c];
    const size_t idx = (size_t)(row0 + r) * OUT_DIM + c;
    Y[idx] = acc;
    unsigned u = __float_as_uint(acc);
    u += 0x7fffu + ((u >> 16) & 1u);      // round-to-nearest-even bf16
    Yh[idx] = (unsigned short)(u >> 16);
  }
}

// ---------------- Phase A: per-block m-histogram + op/seq degree atomics ----------------
__global__ __launch_bounds__(256) void histA_kernel(
    const int* __restrict__ Eseq, const int* __restrict__ Eop2m,
    int* __restrict__ H, int* __restrict__ degOp, int* __restrict__ degSeq) {
  __shared__ int h[N_M];   // 8 KB
  for (int i = threadIdx.x; i < N_M; i += 256) h[i] = 0;
  __syncthreads();
  const int w = blockIdx.x;
  const int e0 = w * CHUNK, e1 = min(E_OP2M_N, e0 + CHUNK);
  for (int e = e0 + threadIdx.x; e < e1; e += 256) {
    atomicAdd(&degOp[Eop2m[e]], 1);
    atomicAdd(&h[Eop2m[E_OP2M_N + e]], 1);
  }
  const int s0 = w * SEQ_CHUNK, s1 = min(E_SEQ_N, s0 + SEQ_CHUNK);
  for (int e = s0 + threadIdx.x; e < s1; e += 256)
    atomicAdd(&degSeq[Eseq[E_SEQ_N + e]], 1);
  __syncthreads();
  for (int i = threadIdx.x; i < N_M; i += 256) H[w * N_M + i] = h[i];
}

// ---------------- Phase B: exclusive column scan of H; degM = column sums ----------------
__global__ __launch_bounds__(512) void colscan_kernel(int* __restrict__ H, int* __restrict__ degM) {
  __shared__ int s[W_BLK];
  const int m = blockIdx.x;
  const int t = threadIdx.x;
  const int v = H[t * N_M + m];
  s[t] = v;
  __syncthreads();
  for (int d = 1; d < W_BLK; d <<= 1) {
    const int x = s[t];
    const int y = (t >= d) ? s[t - d] : 0;
    __syncthreads();
    s[t] = x + y;
    __syncthreads();
  }
  H[t * N_M + m] = s[t] - v;           // exclusive offset of block t within machine m
  if (t == W_BLK - 1) degM[m] = s[W_BLK - 1];
}

// ---------------- baseM: exclusive scan of degM (2000 elems, 1 block) ----------------
__global__ __launch_bounds__(256) void scanM_kernel(
    const int* __restrict__ degM, int* __restrict__ baseM) {
  __shared__ int s[256];
  const int t = threadIdx.x;
  int v[8];
  int sum = 0;
  #pragma unroll
  for (int k = 0; k < 8; ++k) {
    const int i = t * 8 + k;
    v[k] = (i < N_M) ? degM[i] : 0;
    sum += v[k];
  }
  s[t] = sum;
  __syncthreads();
  for (int d = 1; d < 256; d <<= 1) {
    const int x = s[t];
    const int y = (t >= d) ? s[t - d] : 0;
    __syncthreads();
    s[t] = x + y;
    __syncthreads();
  }
  int run = s[t] - sum;
  #pragma unroll
  for (int k = 0; k < 8; ++k) {
    const int i = t * 8 + k;
    if (i < N_M) baseM[i] = run;
    run += v[k];
  }
}

// ---------------- Hierarchical exclusive scan over [degOp|degSeq] ----------------
__global__ __launch_bounds__(256) void scanA_kernel(
    const int* __restrict__ in, int* __restrict__ out, int* __restrict__ blockSums, int n) {
  __shared__ int s[256];
  const int base = blockIdx.x * 1024 + threadIdx.x * 4;
  int v[4];
  #pragma unroll
  for (int k = 0; k < 4; ++k) v[k] = (base + k < n) ? in[base + k] : 0;
  const int tsum = v[0] + v[1] + v[2] + v[3];
  s[threadIdx.x] = tsum;
  __syncthreads();
  for (int d = 1; d < 256; d <<= 1) {
    const int x = s[threadIdx.x];
    const int y = (threadIdx.x >= d) ? s[threadIdx.x - d] : 0;
    __syncthreads();
    s[threadIdx.x] = x + y;
    __syncthreads();
  }
  int run = s[threadIdx.x] - tsum;
  if (threadIdx.x == 255) blockSums[blockIdx.x] = s[255];
  #pragma unroll
  for (int k = 0; k < 4; ++k) {
    if (base + k < n) out[base + k] = run;
    run += v[k];
  }
}

__global__ __launch_bounds__(256) void scanB_kernel(int* __restrict__ bs, int nb) {
  __shared__ int s[256];
  const int t = threadIdx.x;
  const int v = (t < nb) ? bs[t] : 0;
  s[t] = v;
  __syncthreads();
  for (int d = 1; d < 256; d <<= 1) {
    const int x = s[t];
    const int y = (t >= d) ? s[t - d] : 0;
    __syncthreads();
    s[t] = x + y;
    __syncthreads();
  }
  if (t < nb) bs[t] = s[t] - v;
}

__global__ __launch_bounds__(256) void scanC_kernel(
    int* __restrict__ out, const int* __restrict__ bs, int n) {
  const int base = blockIdx.x * 1024 + threadIdx.x * 4;
  const int add = bs[blockIdx.x];
  #pragma unroll
  for (int k = 0; k < 4; ++k)
    if (base + k < n) out[base + k] += add;
}

// ---------------- Fill all three adjacency lists ----------------
__global__ __launch_bounds__(256) void fill_kernel(
    const int* __restrict__ Eseq, const int* __restrict__ Eop2m,
    const int* __restrict__ S, const int* __restrict__ H, const int* __restrict__ baseM,
    int* __restrict__ curOp, int* __restrict__ curSeq,
    int* __restrict__ opL, int* __restrict__ mL, int* __restrict__ seqL) {
  __shared__ int lcur[N_M];   // 8 KB
  for (int i = threadIdx.x; i < N_M; i += 256) lcur[i] = 0;
  __syncthreads();
  const int w = blockIdx.x;
  const int base = w * N_M;
  const int e0 = w * CHUNK, e1 = min(E_OP2M_N, e0 + CHUNK);
  for (int e = e0 + threadIdx.x; e < e1; e += 256) {
    const int op = Eop2m[e];
    const int m  = Eop2m[E_OP2M_N + e];
    opL[S[op] + atomicAdd(&curOp[op], 1)] = m;
    mL[baseM[m] + H[base + m] + atomicAdd(&lcur[m], 1)] = op;
  }
  const int s0 = w * SEQ_CHUNK, s1 = min(E_SEQ_N, s0 + SEQ_CHUNK);
  for (int e = s0 + threadIdx.x; e < s1; e += 256) {
    const int src = Eseq[e];
    const int dst = Eseq[E_SEQ_N + e];
    seqL[(S[OFF_SEQ2 + dst] - E_OP2M_N) + atomicAdd(&curSeq[dst], 1)] = src;
  }
}

// ---------------- op output: one wave per op node, fully fused ----------------
__global__ __launch_bounds__(256) void op_out_kernel(
    const float* __restrict__ HopProj, const float* __restrict__ HmProj,
    const int* __restrict__ S, const int* __restrict__ opL,
    const int* __restrict__ seqL, float* __restrict__ out) {
  const int wid = (blockIdx.x * 256 + threadIdx.x) >> 6;
  if (wid >= N_OP) return;
  const int lane = threadIdx.x & 63;
  const int i = wid;
  float2 acc = *reinterpret_cast<const float2*>(HopProj + (size_t)i * OUT_DIM + lane * 2);

  // seq aggregation (mean over incoming seq edges)
  const int s0 = S[OFF_SEQ2 + i] - E_OP2M_N;
  const int s1 = S[OFF_SEQ2 + i + 1] - E_OP2M_N;
  float2 a = make_float2(0.f, 0.f);
  for (int e = s0; e < s1; ++e) {
    const int src = seqL[e];
    const float2 v = *reinterpret_cast<const float2*>(HopProj + (size_t)src * OUT_DIM + lane * 2);
    a.x += v.x; a.y += v.y;
  }
  const float wS = 1.0f / (float)max(s1 - s0, 1);
  acc.x += a.x * wS; acc.y += a.y * wS;

  // machine aggregation (mean of HmProj over incident op2m edges)
  const int o0 = S[i];
  const int o1 = S[i + 1];
  float2 b = make_float2(0.f, 0.f);
  int e = o0;
  for (; e + 4 <= o1; e += 4) {
    const int m0 = opL[e];
    const int m1 = opL[e + 1];
    const int m2 = opL[e + 2];
    const int m3 = opL[e + 3];
    const float2 v0 = *reinterpret_cast<const float2*>(HmProj + (size_t)m0 * OUT_DIM + lane * 2);
    const float2 v1 = *reinterpret_cast<const float2*>(HmProj + (size_t)m1 * OUT_DIM + lane * 2);
    const float2 v2 = *reinterpret_cast<const float2*>(HmProj + (size_t)m2 * OUT_DIM + lane * 2);
    const float2 v3 = *reinterpret_cast<const float2*>(HmProj + (size_t)m3 * OUT_DIM + lane * 2);
    b.x += (v0.x + v1.x) + (v2.x + v3.x);
    b.y += (v0.y + v1.y) + (v2.y + v3.y);
  }
  for (; e < o1; ++e) {
    const int m0 = opL[e];
    const float2 v0 = *reinterpret_cast<const float2*>(HmProj + (size_t)m0 * OUT_DIM + lane * 2);
    b.x += v0.x; b.y += v0.y;
  }
  const float wO = 1.0f / (float)max(o1 - o0, 1);
  acc.x = fmaxf(acc.x + b.x * wO, 0.f);
  acc.y = fmaxf(acc.y + b.y * wO, 0.f);
  *reinterpret_cast<float2*>(out + (size_t)i * OUT_DIM + lane * 2) = acc;
}

// ---------------- machine output: bf16 gather (256 B/row), fp32 accumulate ----------------
// 512 threads: 16 edge slots x 32 col-quads (ushort4 = 8 B/lane); LDS reduce; fused epilogue.
__global__ __launch_bounds__(512) void m_out_kernel(
    const unsigned short* __restrict__ HopProjH, const float* __restrict__ HmProj,
    const int* __restrict__ mL, const int* __restrict__ baseM, const int* __restrict__ degM,
    float* __restrict__ outM) {
  __shared__ float red[16][129];    // 129 pad: conflict-free column reads in reduce
  const int m = blockIdx.x;
  const int s0 = baseM[m];
  const int deg = degM[m];
  const int c4   = (threadIdx.x & 31) << 2;   // column base 0..124
  const int slot = threadIdx.x >> 5;          // 0..15
  float ax = 0.f, ay = 0.f, az = 0.f, aw = 0.f;
  int e = slot;
  for (; e + 48 < deg; e += 64) {
    const int o0 = mL[s0 + e];
    const int o1 = mL[s0 + e + 16];
    const int o2 = mL[s0 + e + 32];
    const int o3 = mL[s0 + e + 48];
    const ushort4 h0 = *reinterpret_cast<const ushort4*>(HopProjH + (size_t)o0 * OUT_DIM + c4);
    const ushort4 h1 = *reinterpret_cast<const ushort4*>(HopProjH + (size_t)o1 * OUT_DIM + c4);
    const ushort4 h2 = *reinterpret_cast<const ushort4*>(HopProjH + (size_t)o2 * OUT_DIM + c4);
    const ushort4 h3 = *reinterpret_cast<const ushort4*>(HopProjH + (size_t)o3 * OUT_DIM + c4);
    ax += (bf2f(h0.x) + bf2f(h1.x)) + (bf2f(h2.x) + bf2f(h3.x));
    ay += (bf2f(h0.y) + bf2f(h1.y)) + (bf2f(h2.y) + bf2f(h3.y));
    az += (bf2f(h0.z) + bf2f(h1.z)) + (bf2f(h2.z) + bf2f(h3.z));
    aw += (bf2f(h0.w) + bf2f(h1.w)) + (bf2f(h2.w) + bf2f(h3.w));
  }
  for (; e < deg; e += 16) {
    const int o = mL[s0 + e];
    const ushort4 h = *reinterpret_cast<const ushort4*>(HopProjH + (size_t)o * OUT_DIM + c4);
    ax += bf2f(h.x); ay += bf2f(h.y); az += bf2f(h.z); aw += bf2f(h.w);
  }
  red[slot][c4 + 0] = ax;
  red[slot][c4 + 1] = ay;
  red[slot][c4 + 2] = az;
  red[slot][c4 + 3] = aw;
  __syncthreads();
  if (threadIdx.x < 128) {
    const int col = threadIdx.x;
    float s = 0.f;
    #pragma unroll
    for (int k = 0; k < 16; ++k) s += red[k][col];
    const float v = HmProj[m * OUT_DIM + col] + s / (float)max(deg, 1);
    outM[m * OUT_DIM + col] = fmaxf(v, 0.f);
  }
}

extern "C" void kernel_launch(void* const* d_in, const int* in_sizes, int n_in,
                              void* d_out, int out_size, void* d_ws, size_t ws_size,
                              hipStream_t stream) {
  const float* H_op   = (const float*)d_in[0];
  const float* H_m    = (const float*)d_in[1];
  const int*   E_seq  = (const int*)d_in[2];
  const int*   E_op2m = (const int*)d_in[3];
  const float* W_op   = (const float*)d_in[4];
  const float* b_op   = (const float*)d_in[5];
  const float* W_m    = (const float*)d_in[6];
  const float* b_m    = (const float*)d_in[7];
  float* out = (float*)d_out;

  // ---- workspace layout (element offsets, 4B each unless noted) ----
  float* HopProj = (float*)d_ws;                                // 12,800,000
  float* HmProj  = HopProj + (size_t)N_OP * OUT_DIM;            //    256,000
  int*   degOp   = (int*)(HmProj + (size_t)N_M * OUT_DIM);      //    100,000 (zeroed)
  int*   degSeq  = degOp + N_OP;                                //    100,000 (zeroed)
  int*   curOp   = degSeq + N_OP;                               //    100,000 (zeroed)
  int*   curSeq  = curOp + N_OP;                                //    100,000 (zeroed)
  int*   degM    = curSeq + N_OP;                               //      2,048
  int*   baseM   = degM + 2048;                                 //      2,048
  int*   S       = baseM + 2048;                                //    200,704
  int*   bsums   = S + 200704;                                  //        512
  int*   Hh      = bsums + 512;                                 //  1,024,000 (W_BLK * N_M)
  int*   opL     = Hh + (size_t)W_BLK * N_M;                    //  2,000,000
  int*   mL      = opL + E_OP2M_N;                              //  2,000,000
  int*   seqL    = mL + E_OP2M_N;                               //    100,000
  unsigned short* HopProjH = (unsigned short*)(seqL + E_SEQ_N); // 12,800,000 ushort
  unsigned short* HmProjH  = HopProjH + (size_t)N_OP * OUT_DIM; //    256,000 ushort

  // 1. projections (fp32 + bf16 copies)
  proj_kernel<<<(N_OP + 15) / 16, 256, 0, stream>>>(H_op, W_op, b_op, HopProj, HopProjH, N_OP);
  proj_kernel<<<(N_M + 15) / 16, 256, 0, stream>>>(H_m, W_m, b_m, HmProj, HmProjH, N_M);

  // 2. zero degOp/degSeq/curOp/curSeq (contiguous)
  hipMemsetAsync(degOp, 0, (size_t)4 * N_OP * sizeof(int), stream);

  // 3. machine histograms + op/seq degrees
  histA_kernel<<<W_BLK, 256, 0, stream>>>(E_seq, E_op2m, Hh, degOp, degSeq);

  // 4. column scan of H -> per-block offsets + degM; then baseM
  colscan_kernel<<<N_M, W_BLK, 0, stream>>>(Hh, degM);
  scanM_kernel<<<1, 256, 0, stream>>>(degM, baseM);

  // 5. exclusive scan of [degOp|degSeq] -> S
  const int nScanBlocks = (SCAN_N2 + 1023) / 1024;   // 196
  scanA_kernel<<<nScanBlocks, 256, 0, stream>>>(degOp, S, bsums, SCAN_N2);
  scanB_kernel<<<1, 256, 0, stream>>>(bsums, nScanBlocks);
  scanC_kernel<<<nScanBlocks, 256, 0, stream>>>(S, bsums, SCAN_N2);

  // 6. fill adjacency lists
  fill_kernel<<<W_BLK, 256, 0, stream>>>(E_seq, E_op2m, S, Hh, baseM,
                                         curOp, curSeq, opL, mL, seqL);

  // 7. outputs
  {
    const long long threads = (long long)N_OP * 64;
    op_out_kernel<<<(int)((threads + 255) / 256), 256, 0, stream>>>(
        HopProj, HmProj, S, opL, seqL, out);
  }
  m_out_kernel<<<N_M, 512, 0, stream>>>(HopProjH, HmProj, mL, baseM, degM,
                                        out + (size_t)N_OP * OUT_DIM);
}